// Round 4
// baseline (578.432 us; speedup 1.0000x reference)
//
#include <hip/hip_runtime.h>
#include <hip/hip_cooperative_groups.h>
#include <stdint.h>

namespace cg = cooperative_groups;

#define N_ENT 200000
#define NEDGE 4000000
#define RSR 1000
#define RTG 1200
#define DIM 128

#define NBUCK 400     // buckets per side; bucket = head / 500
#define BUCKSZ 500
#define CAP 11264     // mean 10000, sigma ~100 -> +12.6 sigma
#define NE4 (NEDGE / 4)        // 1,000,000 quads per side
#define NCHUNK 977             // chunks of 1024 quads per side
#define PER (NEDGE + N_ENT)    // 4,200,000
#define PER4 (PER / 4)         // 1,050,000
#define GRID 512               // cooperative grid (2 blocks/CU guaranteed)

#define AT2 8                  // fused pools: ceil(1000/128)
#define BT2 19                 // ceil(1200/64)
#define ATILES 16              // fallback pools: ceil(1000/64)
#define BTILES 19

union SharedU {
    struct { unsigned cnt[NBUCK]; unsigned base[NBUCK]; } pa;   // 3.2 KB
    float bins[BUCKSZ];                                         // 2 KB
    struct { float sAT[64][132]; float sBT[64][68]; } pool;     // 50 KB (max)
    struct { float rr[128][17]; float cc[64][17]; } red;        // 12.8 KB (aliases pool, used after sync)
    float norm[256];
};

__device__ __forceinline__ uint32_t to_bf16(float x) {
    uint32_t u = __float_as_uint(x);
    return (u + 0x7FFFu + ((u >> 16) & 1u)) >> 16;   // RTNE
}

// =====================  ONE cooperative kernel, 4 phases  =====================

__global__ __launch_bounds__(256, 2) void fused_kernel(
        const float* __restrict__ emb_sr, const float* __restrict__ emb_tg,
        const float* __restrict__ conf_sr, const float* __restrict__ imp_sr,
        const float* __restrict__ pca_sr,
        const float* __restrict__ conf_tg, const float* __restrict__ imp_tg,
        const float* __restrict__ pca_tg,
        const int* __restrict__ head_sr, const int* __restrict__ tail_sr,
        const int* __restrict__ head_tg, const int* __restrict__ tail_tg,
        float* __restrict__ out,
        float* __restrict__ an, float* __restrict__ bn, float* __restrict__ dis,
        unsigned* __restrict__ gcount, unsigned* __restrict__ regions,
        float* __restrict__ rowpart, float* __restrict__ colpart) {
    cg::grid_group grid = cg::this_grid();
    __shared__ SharedU sh;
    const int t = threadIdx.x, b = blockIdx.x;

    // ---------- P0: normalize embeddings (2 rows/block/iter) + zero gcount ----------
    {
        int half = t >> 7, lt = t & 127;
        for (int r = b * 2 + half; r < RSR + RTG; r += 2 * GRID) {
            // rows come in aligned even/odd pairs and RSR+RTG is even -> block-uniform trips
            const float* src = (r < RSR) ? emb_sr + r * DIM : emb_tg + (r - RSR) * DIM;
            float*       dst = (r < RSR) ? an + r * DIM : bn + (r - RSR) * DIM;
            float x = src[lt];
            sh.norm[t] = x * x;
            __syncthreads();
            for (int off = 64; off > 0; off >>= 1) {
                if (lt < off) sh.norm[t] += sh.norm[t + off];
                __syncthreads();
            }
            dst[lt] = x * rsqrtf(sh.norm[half * 128] + 1e-8f);
            __syncthreads();
        }
        if (b == 0)
            for (int i = t; i < 2 * NBUCK; i += 256) gcount[i] = 0;
    }
    grid.sync();

    // ---------- P1: passA — vectorized multisplit of edges into bucket records ------
    {
        float* out_sr = out;
        float* out_tg = out + PER;
        for (int c = b; c < 2 * NCHUNK; c += GRID) {
            int side = c >= NCHUNK;
            int blk = side ? c - NCHUNK : c;
            const float4* conf4 = (const float4*)(side ? conf_tg : conf_sr);
            const float4* imp4  = (const float4*)(side ? imp_tg  : imp_sr);
            const float4* pca4  = (const float4*)(side ? pca_tg  : pca_sr);
            const int4*   head4 = (const int4*)(side ? head_tg : head_sr);
            float4*       o4    = (float4*)(side ? out_tg : out_sr);

            for (int i = t; i < NBUCK; i += 256) sh.pa.cnt[i] = 0;
            __syncthreads();

            int bkt[16];
            unsigned rec[16], rnk[16];
#pragma unroll
            for (int i = 0; i < 4; i++) {
                int q = blk * 1024 + t + i * 256;
                if (q < NE4) {
                    float4 cf = conf4[q], im = imp4[q], pc = pca4[q];
                    int4 hh = head4[q];
                    float4 v = make_float4(cf.x * im.x * pc.x, cf.y * im.y * pc.y,
                                           cf.z * im.z * pc.z, cf.w * im.w * pc.w);
                    o4[q] = v;                              // stage raw v for finalize
                    const int hs[4] = {hh.x, hh.y, hh.z, hh.w};
                    const float vs[4] = {v.x, v.y, v.z, v.w};
#pragma unroll
                    for (int j = 0; j < 4; j++) {
                        int bb = hs[j] / BUCKSZ;
                        bkt[i * 4 + j] = bb;
                        rec[i * 4 + j] = ((unsigned)(hs[j] - bb * BUCKSZ) << 16) | to_bf16(vs[j]);
                        rnk[i * 4 + j] = atomicAdd(&sh.pa.cnt[bb], 1u);
                    }
                } else {
#pragma unroll
                    for (int j = 0; j < 4; j++) bkt[i * 4 + j] = -1;
                }
            }
            __syncthreads();
            for (int i = t; i < NBUCK; i += 256)
                sh.pa.base[i] = atomicAdd(&gcount[side * NBUCK + i], sh.pa.cnt[i]);
            __syncthreads();
#pragma unroll
            for (int i = 0; i < 16; i++) {
                if (bkt[i] >= 0) {
                    unsigned pos = sh.pa.base[bkt[i]] + rnk[i];
                    if (pos < CAP)
                        regions[(unsigned)(side * NBUCK + bkt[i]) * CAP + pos] = rec[i];
                }
            }
            __syncthreads();   // protect cnt re-zero of next chunk
        }
    }
    grid.sync();

    // ---------- P2: passB bucket jobs (800) + pool tile jobs (152), one job pool ----
    {
        const int NJOBS = 2 * NBUCK + AT2 * BT2;  // 952
        for (int j = b; j < NJOBS; j += GRID) {
            if (j < 2 * NBUCK) {
                // ---- bucket job: LDS accumulate deg, write rsqrt ----
                for (int i = t; i < BUCKSZ; i += 256) sh.bins[i] = 1.0f;  // identity +1
                __syncthreads();
                unsigned n = gcount[j];
                if (n > CAP) n = CAP;
                const unsigned* rp = regions + (size_t)j * CAP;
                for (unsigned i = t; i < n; i += 256) {
                    unsigned r = rp[i];
                    atomicAdd(&sh.bins[r >> 16], __uint_as_float((r & 0xFFFFu) << 16));
                }
                __syncthreads();
                float* dout = dis + (size_t)j * BUCKSZ;
                for (int i = t; i < BUCKSZ; i += 256) dout[i] = rsqrtf(sh.bins[i]);
            } else {
                // ---- pool job: 128x64 tile of An@Bn^T, row/col max partials ----
                int pj = j - 2 * NBUCK;
                int atile = pj & 7, btile = pj >> 3;
                int tx = t & 15, ty = t >> 4;
                float acc[8][4];
#pragma unroll
                for (int r = 0; r < 8; r++)
#pragma unroll
                    for (int cc = 0; cc < 4; cc++) acc[r][cc] = 0.f;
                for (int k0 = 0; k0 < DIM; k0 += 64) {
                    for (int idx = t; idx < 128 * 16; idx += 256) {
                        int row = idx >> 4, q = idx & 15;
                        int ga = atile * 128 + row;
                        float4 v = make_float4(0.f, 0.f, 0.f, 0.f);
                        if (ga < RSR) v = ((const float4*)an)[ga * 32 + (k0 >> 2) + q];
                        sh.pool.sAT[4 * q + 0][row] = v.x;
                        sh.pool.sAT[4 * q + 1][row] = v.y;
                        sh.pool.sAT[4 * q + 2][row] = v.z;
                        sh.pool.sAT[4 * q + 3][row] = v.w;
                    }
                    for (int idx = t; idx < 64 * 16; idx += 256) {
                        int col = idx >> 4, q = idx & 15;
                        int gb = btile * 64 + col;
                        float4 v = make_float4(0.f, 0.f, 0.f, 0.f);
                        if (gb < RTG) v = ((const float4*)bn)[gb * 32 + (k0 >> 2) + q];
                        sh.pool.sBT[4 * q + 0][col] = v.x;
                        sh.pool.sBT[4 * q + 1][col] = v.y;
                        sh.pool.sBT[4 * q + 2][col] = v.z;
                        sh.pool.sBT[4 * q + 3][col] = v.w;
                    }
                    __syncthreads();
                    for (int kk = 0; kk < 64; kk++) {
                        float4 a0 = *(const float4*)&sh.pool.sAT[kk][ty * 8];
                        float4 a1 = *(const float4*)&sh.pool.sAT[kk][ty * 8 + 4];
                        float4 bb = *(const float4*)&sh.pool.sBT[kk][tx * 4];
                        float av[8] = {a0.x, a0.y, a0.z, a0.w, a1.x, a1.y, a1.z, a1.w};
                        float bv[4] = {bb.x, bb.y, bb.z, bb.w};
#pragma unroll
                        for (int r = 0; r < 8; r++)
#pragma unroll
                            for (int cc = 0; cc < 4; cc++)
                                acc[r][cc] = fmaf(av[r], bv[cc], acc[r][cc]);
                    }
                    __syncthreads();
                }
                float rm[8], cm[4];
#pragma unroll
                for (int r = 0; r < 8; r++) rm[r] = -1e30f;
#pragma unroll
                for (int cc = 0; cc < 4; cc++) cm[cc] = -1e30f;
#pragma unroll
                for (int r = 0; r < 8; r++)
#pragma unroll
                    for (int cc = 0; cc < 4; cc++) {
                        bool jok = (btile * 64 + tx * 4 + cc) < RTG;  // mask pad B cols
                        rm[r] = fmaxf(rm[r], jok ? acc[r][cc] : -1e30f);
                        cm[cc] = fmaxf(cm[cc], acc[r][cc]);  // zero A pad rows clamp later
                    }
                __syncthreads();
#pragma unroll
                for (int r = 0; r < 8; r++) sh.red.rr[ty * 8 + r][tx] = rm[r];
#pragma unroll
                for (int cc = 0; cc < 4; cc++) sh.red.cc[tx * 4 + cc][ty] = cm[cc];
                __syncthreads();
                if (t < 128) {
                    float m = sh.red.rr[t][0];
                    for (int x = 1; x < 16; x++) m = fmaxf(m, sh.red.rr[t][x]);
                    int grow = atile * 128 + t;
                    if (grow < RSR) rowpart[btile * 1024 + grow] = m;
                } else if (t < 192) {
                    int col = t - 128;
                    float m = sh.red.cc[col][0];
                    for (int x = 1; x < 16; x++) m = fmaxf(m, sh.red.cc[col][x]);
                    int gcol = btile * 64 + col;
                    if (gcol < RTG) colpart[atile * 1216 + gcol] = m;
                }
            }
            __syncthreads();   // LDS union reuse across jobs
        }
    }
    grid.sync();

    // ---------- P3: rw reduce (blocks 0..8) + finalize (all blocks, float4) ----------
    {
        float* rw_sr = out + 2 * (size_t)PER;
        float* rw_tg = rw_sr + RSR;
        if (b < 9) {
            int idx = b * 256 + t;
            if (idx < 1024) {
                if (idx < RSR) {
                    float m = -1e30f;
                    for (int bt = 0; bt < BT2; bt++) m = fmaxf(m, rowpart[bt * 1024 + idx]);
                    rw_sr[idx] = m;
                }
            } else if (idx < 1024 + RTG) {
                int jj = idx - 1024;
                float m = -1e30f;
                for (int a = 0; a < AT2; a++) m = fmaxf(m, colpart[a * 1216 + jj]);
                rw_tg[jj] = fmaxf(m, 0.0f);  // zero pad rows of A in reference
            }
        }
        for (int Q = b * 256 + t; Q < 2 * PER4; Q += GRID * 256) {
            int side = Q >= PER4;
            int q = side ? Q - PER4 : Q;
            const float* dg = dis + (size_t)side * N_ENT;
            float4* o = (float4*)(out + (size_t)side * PER);
            if (q < NE4) {
                const int4* hd = (const int4*)(side ? head_tg : head_sr);
                const int4* tl = (const int4*)(side ? tail_tg : tail_sr);
                int4 hh = hd[q];
                int4 tt = tl[q];
                float4 v = o[q];
                v.x *= dg[hh.x] * dg[tt.x];
                v.y *= dg[hh.y] * dg[tt.y];
                v.z *= dg[hh.z] * dg[tt.z];
                v.w *= dg[hh.w] * dg[tt.w];
                o[q] = v;
            } else {
                float4 d = ((const float4*)dg)[q - NE4];
                o[q] = make_float4(d.x * d.x, d.y * d.y, d.z * d.z, d.w * d.w);
            }
        }
    }
}

// =====================  Fallback multi-kernel path (proven R3)  =====================

__global__ void prep_kernel(const float* __restrict__ emb_sr, const float* __restrict__ emb_tg,
                            float* __restrict__ an, float* __restrict__ bn,
                            float* __restrict__ dis, unsigned* __restrict__ gcount) {
    int blk = blockIdx.x, t = threadIdx.x;
    if (blk < RSR + RTG) {
        const float* src; float* dst; int row;
        if (blk < RSR) { src = emb_sr; dst = an; row = blk; }
        else           { src = emb_tg; dst = bn; row = blk - RSR; }
        float x = src[row * DIM + t];
        __shared__ float shm[DIM];
        shm[t] = x * x;
        __syncthreads();
        for (int off = 64; off > 0; off >>= 1) {
            if (t < off) shm[t] += shm[t + off];
            __syncthreads();
        }
        dst[row * DIM + t] = x * rsqrtf(shm[0] + 1e-8f);
        if (blk == 0)
            for (int i = t; i < 2 * NBUCK; i += DIM) gcount[i] = 0;
    } else {
        int bb = blk - (RSR + RTG);
        for (int i = t; i < 1000; i += DIM) dis[bb * 1000 + i] = 1.0f;
    }
}

__global__ void scatter_atomic_kernel(
        const float* __restrict__ conf_sr, const float* __restrict__ imp_sr,
        const float* __restrict__ pca_sr,
        const float* __restrict__ conf_tg, const float* __restrict__ imp_tg,
        const float* __restrict__ pca_tg,
        const int* __restrict__ head_sr, const int* __restrict__ head_tg,
        float* __restrict__ out_sr, float* __restrict__ out_tg,
        float* __restrict__ deg) {
    int e = blockIdx.x * blockDim.x + threadIdx.x;
    if (e < NEDGE) {
        float v = conf_sr[e] * imp_sr[e] * pca_sr[e];
        out_sr[e] = v;
        unsafeAtomicAdd(&deg[head_sr[e]], v);
    } else if (e < 2 * NEDGE) {
        int i = e - NEDGE;
        float v = conf_tg[i] * imp_tg[i] * pca_tg[i];
        out_tg[i] = v;
        unsafeAtomicAdd(&deg[N_ENT + head_tg[i]], v);
    }
}

__global__ void rsqrt_kernel(float* __restrict__ dis) {
    int i = blockIdx.x * blockDim.x + threadIdx.x;
    if (i < 2 * N_ENT) dis[i] = rsqrtf(dis[i]);
}

__global__ __launch_bounds__(256) void finalize_kernel(
        const int* __restrict__ head_sr, const int* __restrict__ tail_sr,
        const int* __restrict__ head_tg, const int* __restrict__ tail_tg,
        const float* __restrict__ dis, float* __restrict__ out) {
    int idx = blockIdx.x * blockDim.x + threadIdx.x;
    if (idx >= 2 * PER4) return;
    int side = idx >= PER4 ? 1 : 0;
    int q = side ? idx - PER4 : idx;
    const float* dg = dis + (size_t)side * N_ENT;
    float4* o = (float4*)(out + (size_t)side * PER);
    if (q < NE4) {
        const int4* hd = (const int4*)(side ? head_tg : head_sr);
        const int4* tl = (const int4*)(side ? tail_tg : tail_sr);
        int4 hh = hd[q];
        int4 tt = tl[q];
        float4 v = o[q];
        v.x *= dg[hh.x] * dg[tt.x];
        v.y *= dg[hh.y] * dg[tt.y];
        v.z *= dg[hh.z] * dg[tt.z];
        v.w *= dg[hh.w] * dg[tt.w];
        o[q] = v;
    } else {
        float4 d = ((const float4*)dg)[q - NE4];
        o[q] = make_float4(d.x * d.x, d.y * d.y, d.z * d.z, d.w * d.w);
    }
}

__global__ __launch_bounds__(256) void pools_tiles_kernel(
        const float* __restrict__ an, const float* __restrict__ bn,
        float* __restrict__ rowpart, float* __restrict__ colpart) {
    __shared__ float sA[64][132];
    __shared__ float sB[64][133];
    __shared__ float rr[64][17];
    __shared__ float cc[64][17];
    int t = threadIdx.x;
    int atile = blockIdx.x % ATILES;
    int btile = blockIdx.x / ATILES;
    for (int idx = t; idx < 64 * 32; idx += 256) {
        int row = idx >> 5, k4 = idx & 31;
        int ga = atile * 64 + row;
        float4 va = (ga < RSR) ? ((const float4*)(an + ga * DIM))[k4]
                               : make_float4(0.f, 0.f, 0.f, 0.f);
        *(float4*)&sA[row][k4 * 4] = va;
        int gb = btile * 64 + row;
        float4 vb = (gb < RTG) ? ((const float4*)(bn + gb * DIM))[k4]
                               : make_float4(0.f, 0.f, 0.f, 0.f);
        sB[row][k4 * 4 + 0] = vb.x; sB[row][k4 * 4 + 1] = vb.y;
        sB[row][k4 * 4 + 2] = vb.z; sB[row][k4 * 4 + 3] = vb.w;
    }
    __syncthreads();
    int tx = t & 15, ty = t >> 4;
    float acc[4][4] = {};
    for (int k4 = 0; k4 < 32; k4++) {
        float4 a4[4];
#pragma unroll
        for (int r = 0; r < 4; r++) a4[r] = *(const float4*)&sA[ty * 4 + r][k4 * 4];
#pragma unroll
        for (int kk = 0; kk < 4; kk++) {
            float bvv[4];
#pragma unroll
            for (int c = 0; c < 4; c++) bvv[c] = sB[tx * 4 + c][k4 * 4 + kk];
            float avv[4];
#pragma unroll
            for (int r = 0; r < 4; r++)
                avv[r] = kk == 0 ? a4[r].x : kk == 1 ? a4[r].y : kk == 2 ? a4[r].z : a4[r].w;
#pragma unroll
            for (int r = 0; r < 4; r++)
#pragma unroll
                for (int c = 0; c < 4; c++) acc[r][c] = fmaf(avv[r], bvv[c], acc[r][c]);
        }
    }
    float rm[4] = {-1e30f, -1e30f, -1e30f, -1e30f};
    float cm[4] = {-1e30f, -1e30f, -1e30f, -1e30f};
#pragma unroll
    for (int r = 0; r < 4; r++)
#pragma unroll
        for (int c = 0; c < 4; c++) {
            bool jok = (btile * 64 + tx * 4 + c) < RTG;
            rm[r] = fmaxf(rm[r], jok ? acc[r][c] : -1e30f);
            cm[c] = fmaxf(cm[c], acc[r][c]);
        }
#pragma unroll
    for (int r = 0; r < 4; r++) rr[ty * 4 + r][tx] = rm[r];
#pragma unroll
    for (int c = 0; c < 4; c++) cc[tx * 4 + c][ty] = cm[c];
    __syncthreads();
    if (t < 64) {
        float m = rr[t][0];
        for (int x = 1; x < 16; x++) m = fmaxf(m, rr[t][x]);
        rowpart[btile * 1024 + atile * 64 + t] = m;
        float m2 = cc[t][0];
        for (int x = 1; x < 16; x++) m2 = fmaxf(m2, cc[t][x]);
        colpart[atile * 1216 + btile * 64 + t] = m2;
    }
}

__global__ void rw_reduce_kernel(const float* __restrict__ rowpart,
                                 const float* __restrict__ colpart,
                                 float* __restrict__ rw_sr, float* __restrict__ rw_tg) {
    int idx = blockIdx.x * blockDim.x + threadIdx.x;
    if (idx < 1024) {
        if (idx < RSR) {
            float m = -1e30f;
            for (int bb = 0; bb < BTILES; bb++) m = fmaxf(m, rowpart[bb * 1024 + idx]);
            rw_sr[idx] = m;
        }
    } else {
        int j = idx - 1024;
        if (j < RTG) {
            float m = -1e30f;
            for (int a = 0; a < ATILES; a++) m = fmaxf(m, colpart[a * 1216 + j]);
            rw_tg[j] = fmaxf(m, 0.0f);
        }
    }
}

// =====================  host  =====================

extern "C" void kernel_launch(void* const* d_in, const int* in_sizes, int n_in,
                              void* d_out, int out_size, void* d_ws, size_t ws_size,
                              hipStream_t stream) {
    const float* rel_emb_sr = (const float*)d_in[0];
    const float* rel_emb_tg = (const float*)d_in[1];
    const float* conf_sr = (const float*)d_in[2];
    const float* imp_sr  = (const float*)d_in[3];
    const float* pca_sr  = (const float*)d_in[4];
    const float* conf_tg = (const float*)d_in[5];
    const float* imp_tg  = (const float*)d_in[6];
    const float* pca_tg  = (const float*)d_in[7];
    const int* head_sr = (const int*)d_in[8];
    const int* tail_sr = (const int*)d_in[9];
    const int* head_tg = (const int*)d_in[11];
    const int* tail_tg = (const int*)d_in[12];

    float* out = (float*)d_out;
    float* rw_sr = out + 2 * (size_t)PER;
    float* rw_tg = rw_sr + RSR;

    float* ws = (float*)d_ws;
    float* an  = ws;                                   // 128,000
    float* bn  = an + RSR * DIM;                       // 153,600
    float* dis = bn + RTG * DIM;                       // 400,000
    unsigned* gcount  = (unsigned*)(dis + 2 * N_ENT);  // 800
    unsigned* regions = gcount + 2 * NBUCK;            // 9,011,200
    float* rowpart = (float*)(regions + (size_t)2 * NBUCK * CAP);  // 19,456
    float* colpart = rowpart + 19456;                              // 19,456 (max of both paths)

    size_t need = ((size_t)(RSR * DIM + RTG * DIM + 2 * N_ENT + 2 * NBUCK) +
                   (size_t)2 * NBUCK * CAP + 19456 + 19456) * 4;

    if (ws_size >= need) {
        void* args[] = {
            (void*)&rel_emb_sr, (void*)&rel_emb_tg,
            (void*)&conf_sr, (void*)&imp_sr, (void*)&pca_sr,
            (void*)&conf_tg, (void*)&imp_tg, (void*)&pca_tg,
            (void*)&head_sr, (void*)&tail_sr, (void*)&head_tg, (void*)&tail_tg,
            (void*)&out, (void*)&an, (void*)&bn, (void*)&dis,
            (void*)&gcount, (void*)&regions, (void*)&rowpart, (void*)&colpart,
        };
        hipLaunchCooperativeKernel((const void*)fused_kernel, dim3(GRID), dim3(256),
                                   args, 0, stream);
    } else {
        // fallback: proven multi-kernel pipeline with global atomics
        float* out_sr = out;
        float* out_tg = out + PER;
        hipLaunchKernelGGL(prep_kernel, dim3(RSR + RTG + 400), dim3(DIM), 0, stream,
                           rel_emb_sr, rel_emb_tg, an, bn, dis, gcount);
        hipLaunchKernelGGL(scatter_atomic_kernel, dim3((2 * NEDGE + 255) / 256), dim3(256),
                           0, stream,
                           conf_sr, imp_sr, pca_sr, conf_tg, imp_tg, pca_tg,
                           head_sr, head_tg, out_sr, out_tg, dis);
        hipLaunchKernelGGL(rsqrt_kernel, dim3((2 * N_ENT + 255) / 256), dim3(256), 0, stream,
                           dis);
        hipLaunchKernelGGL(pools_tiles_kernel, dim3(ATILES * BTILES), dim3(256), 0, stream,
                           an, bn, rowpart, colpart);
        hipLaunchKernelGGL(rw_reduce_kernel, dim3((1024 + 1216 + 255) / 256), dim3(256),
                           0, stream, rowpart, colpart, rw_sr, rw_tg);
        hipLaunchKernelGGL(finalize_kernel, dim3((2 * PER4 + 255) / 256), dim3(256), 0, stream,
                           head_sr, tail_sr, head_tg, tail_tg, dis, out);
    }
}

// Round 5
// 377.224 us; speedup vs baseline: 1.5334x; 1.5334x over previous
//
#include <hip/hip_runtime.h>
#include <stdint.h>

#define N_ENT 200000
#define NEDGE 4000000
#define RSR 1000
#define RTG 1200
#define DIM 128

#define NBUCK 400              // buckets per side; bucket = head / 500
#define BUCKSZ 500
#define CAP 11264              // mean 10000, sigma ~100 -> +12.6 sigma
#define CHUNK 4096             // edges per passA block (1024 quads)
#define NE4 (NEDGE / 4)        // 1,000,000
#define NBLK 977               // ceil(NE4 / 1024)
#define PER (NEDGE + N_ENT)    // 4,200,000
#define PER4 (PER / 4)
#define ATILES 16
#define BTILES 19

__device__ __forceinline__ uint32_t to_bf16(float x) {
    uint32_t u = __float_as_uint(x);
    return (u + 0x7FFFu + ((u >> 16) & 1u)) >> 16;   // RTNE
}

// ---------------- kernel 1: prep ----------------------------------------------------

__global__ void prep_kernel(const float* __restrict__ emb_sr, const float* __restrict__ emb_tg,
                            float* __restrict__ an, float* __restrict__ bn,
                            float* __restrict__ dis, unsigned* __restrict__ gcount) {
    int blk = blockIdx.x, t = threadIdx.x;  // 128 threads
    if (blk < RSR + RTG) {
        const float* src; float* dst; int row;
        if (blk < RSR) { src = emb_sr; dst = an; row = blk; }
        else           { src = emb_tg; dst = bn; row = blk - RSR; }
        float x = src[row * DIM + t];
        __shared__ float sh[DIM];
        sh[t] = x * x;
        __syncthreads();
        for (int off = 64; off > 0; off >>= 1) {
            if (t < off) sh[t] += sh[t + off];
            __syncthreads();
        }
        dst[row * DIM + t] = x * rsqrtf(sh[0] + 1e-8f);
        if (blk == 0)
            for (int i = t; i < 2 * NBUCK; i += DIM) gcount[i] = 0;
    } else {
        // dis = 1.0 init — only the atomic fallback path needs it (passB overwrites)
        int b = blk - (RSR + RTG);
        for (int i = t; i < 1000; i += DIM) dis[b * 1000 + i] = 1.0f;
    }
}

// ---------------- kernel 2: passA — LDS counting-sort multisplit --------------------
// histogram(rank) -> scan -> place sorted in LDS -> coalesced flush to bucket regions

__global__ __launch_bounds__(256) void passA_kernel(
        const float* __restrict__ conf_sr, const float* __restrict__ imp_sr,
        const float* __restrict__ pca_sr,
        const float* __restrict__ conf_tg, const float* __restrict__ imp_tg,
        const float* __restrict__ pca_tg,
        const int* __restrict__ head_sr, const int* __restrict__ head_tg,
        float* __restrict__ out_sr, float* __restrict__ out_tg,
        unsigned* __restrict__ gcount, unsigned* __restrict__ regions) {
    __shared__ unsigned cnt[NBUCK];
    __shared__ unsigned scan_a[512];
    __shared__ unsigned scan_b[512];
    __shared__ unsigned offs[NBUCK];
    __shared__ unsigned gdst[NBUCK];
    __shared__ unsigned stage[CHUNK];
    __shared__ unsigned short aux[CHUNK];

    const int t = threadIdx.x;
    const int side = (int)blockIdx.x >= NBLK;
    const int blk = side ? blockIdx.x - NBLK : blockIdx.x;
    const float4* conf4 = (const float4*)(side ? conf_tg : conf_sr);
    const float4* imp4  = (const float4*)(side ? imp_tg  : imp_sr);
    const float4* pca4  = (const float4*)(side ? pca_tg  : pca_sr);
    const int4*   head4 = (const int4*)(side ? head_tg : head_sr);
    float4*       o4    = (float4*)(side ? out_tg : out_sr);

    for (int i = t; i < NBUCK; i += 256) cnt[i] = 0;
    __syncthreads();

    // load quads, compute v, stage raw v to out, histogram with rank
    int bkt[16];
    unsigned rec[16], rnk[16];
#pragma unroll
    for (int i = 0; i < 4; i++) {
        int q = blk * 1024 + t + i * 256;
        if (q < NE4) {
            float4 cf = conf4[q], im = imp4[q], pc = pca4[q];
            int4 hh = head4[q];
            float4 v = make_float4(cf.x * im.x * pc.x, cf.y * im.y * pc.y,
                                   cf.z * im.z * pc.z, cf.w * im.w * pc.w);
            o4[q] = v;
            const int hs[4] = {hh.x, hh.y, hh.z, hh.w};
            const float vs[4] = {v.x, v.y, v.z, v.w};
#pragma unroll
            for (int j = 0; j < 4; j++) {
                int bb = hs[j] / BUCKSZ;
                bkt[i * 4 + j] = bb;
                rec[i * 4 + j] = ((unsigned)(hs[j] - bb * BUCKSZ) << 16) | to_bf16(vs[j]);
                rnk[i * 4 + j] = atomicAdd(&cnt[bb], 1u);
            }
        } else {
#pragma unroll
            for (int j = 0; j < 4; j++) bkt[i * 4 + j] = -1;
        }
    }
    __syncthreads();

    // inclusive Hillis-Steele scan of cnt over 512 padded slots
    for (int i = t; i < 512; i += 256) scan_a[i] = (i < NBUCK) ? cnt[i] : 0;
    __syncthreads();
    unsigned* src = scan_a;
    unsigned* dst = scan_b;
    for (int s = 1; s < 512; s <<= 1) {
        for (int i = t; i < 512; i += 256)
            dst[i] = src[i] + (i >= s ? src[i - s] : 0u);
        __syncthreads();
        unsigned* tmp = src; src = dst; dst = tmp;
    }
    for (int i = t; i < NBUCK; i += 256) offs[i] = src[i] - cnt[i];
    __syncthreads();

    // place records sorted by bucket into LDS stage
#pragma unroll
    for (int i = 0; i < 16; i++) {
        if (bkt[i] >= 0) {
            unsigned pos = offs[bkt[i]] + rnk[i];
            stage[pos] = rec[i];
            aux[pos] = (unsigned short)bkt[i];
        }
    }
    // reserve global space per bucket (one atomic per bucket per block)
    for (int i = t; i < NBUCK; i += 256) {
        unsigned gb = atomicAdd(&gcount[side * NBUCK + i], cnt[i]);
        gdst[i] = (unsigned)(side * NBUCK + i) * CAP + gb - offs[i];
    }
    __syncthreads();

    // coalesced flush: consecutive LDS slots -> contiguous per-bucket runs in global
    unsigned total = src[NBUCK - 1];
    for (int i = t; i < (int)total; i += 256) {
        unsigned b = aux[i];
        unsigned d = gdst[b] + i;
        if (d < (unsigned)(side * NBUCK + b + 1) * CAP) regions[d] = stage[i];
    }
}

// ---------------- kernel 3: passB — per-bucket LDS accumulate, write rsqrt ----------

__global__ __launch_bounds__(256) void passB_kernel(const unsigned* __restrict__ regions,
                                                    const unsigned* __restrict__ gcount,
                                                    float* __restrict__ dis) {
    __shared__ float bins[BUCKSZ];
    int t = threadIdx.x;
    for (int i = t; i < BUCKSZ; i += 256) bins[i] = 1.0f;  // identity +1
    __syncthreads();
    unsigned n = gcount[blockIdx.x];
    if (n > CAP) n = CAP;
    const unsigned* rp = regions + (size_t)blockIdx.x * CAP;
    for (unsigned i = t; i < n; i += 256) {
        unsigned rec = rp[i];
        atomicAdd(&bins[rec >> 16], __uint_as_float((rec & 0xFFFFu) << 16));
    }
    __syncthreads();
    float* dout = dis + (size_t)blockIdx.x * BUCKSZ;
    for (int i = t; i < BUCKSZ; i += 256) dout[i] = rsqrtf(bins[i]);
}

// ---------------- fallback: global-atomic scatter + rsqrt ---------------------------

__global__ void scatter_atomic_kernel(
        const float* __restrict__ conf_sr, const float* __restrict__ imp_sr,
        const float* __restrict__ pca_sr,
        const float* __restrict__ conf_tg, const float* __restrict__ imp_tg,
        const float* __restrict__ pca_tg,
        const int* __restrict__ head_sr, const int* __restrict__ head_tg,
        float* __restrict__ out_sr, float* __restrict__ out_tg,
        float* __restrict__ deg) {
    int e = blockIdx.x * blockDim.x + threadIdx.x;
    if (e < NEDGE) {
        float v = conf_sr[e] * imp_sr[e] * pca_sr[e];
        out_sr[e] = v;
        unsafeAtomicAdd(&deg[head_sr[e]], v);
    } else if (e < 2 * NEDGE) {
        int i = e - NEDGE;
        float v = conf_tg[i] * imp_tg[i] * pca_tg[i];
        out_tg[i] = v;
        unsafeAtomicAdd(&deg[N_ENT + head_tg[i]], v);
    }
}

__global__ void rsqrt_kernel(float* __restrict__ dis) {
    int i = blockIdx.x * blockDim.x + threadIdx.x;
    if (i < 2 * N_ENT) dis[i] = rsqrtf(dis[i]);
}

// ---------------- kernel 4: finalize (float4) ---------------------------------------

__global__ __launch_bounds__(256) void finalize_kernel(
        const int* __restrict__ head_sr, const int* __restrict__ tail_sr,
        const int* __restrict__ head_tg, const int* __restrict__ tail_tg,
        const float* __restrict__ dis, float* __restrict__ out) {
    int idx = blockIdx.x * blockDim.x + threadIdx.x;
    if (idx >= 2 * PER4) return;
    int side = idx >= PER4 ? 1 : 0;
    int q = side ? idx - PER4 : idx;
    const float* dg = dis + (size_t)side * N_ENT;
    float4* o = (float4*)(out + (size_t)side * PER);
    if (q < NE4) {
        const int4* hd = (const int4*)(side ? head_tg : head_sr);
        const int4* tl = (const int4*)(side ? tail_tg : tail_sr);
        int4 hh = hd[q];
        int4 tt = tl[q];
        float4 v = o[q];
        v.x *= dg[hh.x] * dg[tt.x];
        v.y *= dg[hh.y] * dg[tt.y];
        v.z *= dg[hh.z] * dg[tt.z];
        v.w *= dg[hh.w] * dg[tt.w];
        o[q] = v;
    } else {
        float4 d = ((const float4*)dg)[q - NE4];
        o[q] = make_float4(d.x * d.x, d.y * d.y, d.z * d.z, d.w * d.w);
    }
}

// ---------------- kernel 5: tiled sim matrix, row/col max partials ------------------

__global__ __launch_bounds__(256) void pools_tiles_kernel(
        const float* __restrict__ an, const float* __restrict__ bn,
        float* __restrict__ rowpart, float* __restrict__ colpart) {
    __shared__ float sA[64][132];
    __shared__ float sB[64][133];
    __shared__ float rr[64][17];
    __shared__ float cc[64][17];
    int t = threadIdx.x;
    int atile = blockIdx.x % ATILES;
    int btile = blockIdx.x / ATILES;
    for (int idx = t; idx < 64 * 32; idx += 256) {
        int row = idx >> 5, k4 = idx & 31;
        int ga = atile * 64 + row;
        float4 va = (ga < RSR) ? ((const float4*)(an + ga * DIM))[k4]
                               : make_float4(0.f, 0.f, 0.f, 0.f);
        *(float4*)&sA[row][k4 * 4] = va;
        int gb = btile * 64 + row;
        float4 vb = (gb < RTG) ? ((const float4*)(bn + gb * DIM))[k4]
                               : make_float4(0.f, 0.f, 0.f, 0.f);
        sB[row][k4 * 4 + 0] = vb.x; sB[row][k4 * 4 + 1] = vb.y;
        sB[row][k4 * 4 + 2] = vb.z; sB[row][k4 * 4 + 3] = vb.w;
    }
    __syncthreads();
    int tx = t & 15, ty = t >> 4;
    float acc[4][4] = {};
    for (int k4 = 0; k4 < 32; k4++) {
        float4 a4[4];
#pragma unroll
        for (int r = 0; r < 4; r++) a4[r] = *(const float4*)&sA[ty * 4 + r][k4 * 4];
#pragma unroll
        for (int kk = 0; kk < 4; kk++) {
            float bv[4];
#pragma unroll
            for (int c = 0; c < 4; c++) bv[c] = sB[tx * 4 + c][k4 * 4 + kk];
            float av[4];
#pragma unroll
            for (int r = 0; r < 4; r++)
                av[r] = kk == 0 ? a4[r].x : kk == 1 ? a4[r].y : kk == 2 ? a4[r].z : a4[r].w;
#pragma unroll
            for (int r = 0; r < 4; r++)
#pragma unroll
                for (int c = 0; c < 4; c++) acc[r][c] = fmaf(av[r], bv[c], acc[r][c]);
        }
    }
    float rm[4] = {-1e30f, -1e30f, -1e30f, -1e30f};
    float cm[4] = {-1e30f, -1e30f, -1e30f, -1e30f};
#pragma unroll
    for (int r = 0; r < 4; r++)
#pragma unroll
        for (int c = 0; c < 4; c++) {
            bool jok = (btile * 64 + tx * 4 + c) < RTG;   // mask pad B cols
            rm[r] = fmaxf(rm[r], jok ? acc[r][c] : -1e30f);
            cm[c] = fmaxf(cm[c], acc[r][c]);              // ref zero-pads A rows
        }
#pragma unroll
    for (int r = 0; r < 4; r++) rr[ty * 4 + r][tx] = rm[r];
#pragma unroll
    for (int c = 0; c < 4; c++) cc[tx * 4 + c][ty] = cm[c];
    __syncthreads();
    if (t < 64) {
        float m = rr[t][0];
        for (int x = 1; x < 16; x++) m = fmaxf(m, rr[t][x]);
        rowpart[btile * 1024 + atile * 64 + t] = m;
        float m2 = cc[t][0];
        for (int x = 1; x < 16; x++) m2 = fmaxf(m2, cc[t][x]);
        colpart[atile * 1216 + btile * 64 + t] = m2;
    }
}

// ---------------- kernel 6: reduce partial maxes ------------------------------------

__global__ void rw_reduce_kernel(const float* __restrict__ rowpart,
                                 const float* __restrict__ colpart,
                                 float* __restrict__ rw_sr, float* __restrict__ rw_tg) {
    int idx = blockIdx.x * blockDim.x + threadIdx.x;
    if (idx < 1024) {
        if (idx < RSR) {
            float m = -1e30f;
            for (int b = 0; b < BTILES; b++) m = fmaxf(m, rowpart[b * 1024 + idx]);
            rw_sr[idx] = m;
        }
    } else {
        int j = idx - 1024;
        if (j < RTG) {
            float m = -1e30f;
            for (int a = 0; a < ATILES; a++) m = fmaxf(m, colpart[a * 1216 + j]);
            rw_tg[j] = fmaxf(m, 0.0f);  // zero pad rows of A in reference
        }
    }
}

// ---------------- host ---------------------------------------------------------------

extern "C" void kernel_launch(void* const* d_in, const int* in_sizes, int n_in,
                              void* d_out, int out_size, void* d_ws, size_t ws_size,
                              hipStream_t stream) {
    const float* rel_emb_sr = (const float*)d_in[0];
    const float* rel_emb_tg = (const float*)d_in[1];
    const float* conf_sr = (const float*)d_in[2];
    const float* imp_sr  = (const float*)d_in[3];
    const float* pca_sr  = (const float*)d_in[4];
    const float* conf_tg = (const float*)d_in[5];
    const float* imp_tg  = (const float*)d_in[6];
    const float* pca_tg  = (const float*)d_in[7];
    const int* head_sr = (const int*)d_in[8];
    const int* tail_sr = (const int*)d_in[9];
    const int* head_tg = (const int*)d_in[11];
    const int* tail_tg = (const int*)d_in[12];

    float* out = (float*)d_out;
    float* out_sr = out;
    float* out_tg = out + PER;
    float* rw_sr  = out + 2 * (size_t)PER;
    float* rw_tg  = rw_sr + RSR;

    float* ws = (float*)d_ws;
    float* an  = ws;                                   // RSR*DIM
    float* bn  = an + RSR * DIM;                       // RTG*DIM
    float* dis = bn + RTG * DIM;                       // 2*N_ENT (rsqrt(deg))
    unsigned* gcount  = (unsigned*)(dis + 2 * N_ENT);  // 2*NBUCK
    unsigned* regions = gcount + 2 * NBUCK;            // 2*NBUCK*CAP
    float* rowpart = (float*)(regions + (size_t)2 * NBUCK * CAP);  // BTILES*1024
    float* colpart = rowpart + BTILES * 1024;                      // ATILES*1216

    size_t need = ((size_t)(RSR * DIM + RTG * DIM + 2 * N_ENT + 2 * NBUCK) +
                   (size_t)2 * NBUCK * CAP + BTILES * 1024 + ATILES * 1216) * 4;
    bool bucketed = ws_size >= need;

    // 1. prep: normalize embeddings, zero gcount, dis=1
    hipLaunchKernelGGL(prep_kernel, dim3(RSR + RTG + 400), dim3(DIM), 0, stream,
                       rel_emb_sr, rel_emb_tg, an, bn, dis, gcount);

    if (bucketed) {
        // 2. passA: LDS counting-sort multisplit (coalesced region writes)
        hipLaunchKernelGGL(passA_kernel, dim3(2 * NBLK), dim3(256), 0, stream,
                           conf_sr, imp_sr, pca_sr, conf_tg, imp_tg, pca_tg,
                           head_sr, head_tg, out_sr, out_tg, gcount, regions);
        // 3. passB: per-bucket LDS accumulate -> dis = rsqrt(deg)
        hipLaunchKernelGGL(passB_kernel, dim3(2 * NBUCK), dim3(256), 0, stream,
                           regions, gcount, dis);
    } else {
        hipLaunchKernelGGL(scatter_atomic_kernel, dim3((2 * NEDGE + 255) / 256), dim3(256),
                           0, stream,
                           conf_sr, imp_sr, pca_sr, conf_tg, imp_tg, pca_tg,
                           head_sr, head_tg, out_sr, out_tg, dis);
        hipLaunchKernelGGL(rsqrt_kernel, dim3((2 * N_ENT + 255) / 256), dim3(256), 0, stream,
                           dis);
    }

    // 4. pools: tiled sim + partial maxes
    hipLaunchKernelGGL(pools_tiles_kernel, dim3(ATILES * BTILES), dim3(256), 0, stream,
                       an, bn, rowpart, colpart);
    hipLaunchKernelGGL(rw_reduce_kernel, dim3((1024 + 1216 + 255) / 256), dim3(256), 0, stream,
                       rowpart, colpart, rw_sr, rw_tg);

    // 5. finalize: out[e] = v * dis[head] * dis[tail]; diagonal = dis^2
    hipLaunchKernelGGL(finalize_kernel, dim3((2 * PER4 + 255) / 256), dim3(256), 0, stream,
                       head_sr, tail_sr, head_tg, tail_tg, dis, out);
}